// Round 8
// baseline (216.334 us; speedup 1.0000x reference)
//
#include <hip/hip_runtime.h>
#include <math.h>

#define NPIX 4096        // N = H*W = 64*64
#define CCH 8            // channels
#define BLK 256          // 4 waves per block
#define NW   (BLK/64)
#define RPW  8           // rows per wave
#define TILE (NW*RPW)    // 32 rows per block
#define L2E 1.44269504088896340736f

typedef float floatx4 __attribute__((ext_vector_type(4)));

// ---------------- Kernel A: k/v projection, x read ONCE ----------------
__global__ __launch_bounds__(256) void kv_project(
    const float* __restrict__ x,
    const float* __restrict__ Wk, const float* __restrict__ bk,
    const float* __restrict__ Wv, const float* __restrict__ bv,
    float* __restrict__ kbuf, float* __restrict__ vbuf)
{
    const int b = blockIdx.y;
    const int j = blockIdx.x * 256 + threadIdx.x;

    float wk[CCH], wv[CCH];
#pragma unroll
    for (int c = 0; c < CCH; ++c) { wk[c] = Wk[c]; wv[c] = Wv[c]; }
    const float bkv = bk[0], bvv = bv[0];

    const float4* xp = reinterpret_cast<const float4*>(x + ((size_t)b * NPIX + j) * CCH);
    float4 x0 = xp[0];
    float4 x1 = xp[1];
    float kj = bkv;
    kj = fmaf(x0.x, wk[0], kj); kj = fmaf(x0.y, wk[1], kj);
    kj = fmaf(x0.z, wk[2], kj); kj = fmaf(x0.w, wk[3], kj);
    kj = fmaf(x1.x, wk[4], kj); kj = fmaf(x1.y, wk[5], kj);
    kj = fmaf(x1.z, wk[6], kj); kj = fmaf(x1.w, wk[7], kj);
    float vj = bvv;
    vj = fmaf(x0.x, wv[0], vj); vj = fmaf(x0.y, wv[1], vj);
    vj = fmaf(x0.z, wv[2], vj); vj = fmaf(x0.w, wv[3], vj);
    vj = fmaf(x1.x, wv[4], vj); vj = fmaf(x1.y, wv[5], vj);
    vj = fmaf(x1.z, wv[6], vj); vj = fmaf(x1.w, wv[7], vj);

    kbuf[(size_t)b * NPIX + j] = kj;
    vbuf[(size_t)b * NPIX + j] = vj;
}

// -------- Kernel B: wave-autonomous rows, barrier-free store stream --------
__global__ __launch_bounds__(BLK, 4) void attn_main(
    const float* __restrict__ x,
    const float* __restrict__ Wq, const float* __restrict__ bq,
    const float* __restrict__ gamma_p,
    const float* __restrict__ kbuf, const float* __restrict__ vbuf,
    float* __restrict__ y, float* __restrict__ attn)
{
    __shared__ float ks[NPIX];
    __shared__ float vs[NPIX];
    __shared__ float kred[2][NW];

    const int b = blockIdx.y;
    const int rowbase = blockIdx.x * TILE;
    const int tid = threadIdx.x;
    const int wid = tid >> 6;
    const int lane = tid & 63;

    float wq[CCH];
#pragma unroll
    for (int c = 0; c < CCH; ++c) wq[c] = Wq[c];
    const float bqv = bq[0];
    const float gamma = gamma_p[0];

    const float* xb = x + (size_t)b * NPIX * CCH;
    const float4* kb4 = reinterpret_cast<const float4*>(kbuf + (size_t)b * NPIX);
    const float4* vb4 = reinterpret_cast<const float4*>(vbuf + (size_t)b * NPIX);

    // ---- stage k,v into LDS (32 KB from ws); k min/max on the fly ----
    float kmx = -INFINITY, kmn = INFINITY;
#pragma unroll
    for (int i = 0; i < 4; ++i) {
        const int idx = tid + i * 256;           // float4 index
        float4 kk = kb4[idx];
        float4 vv = vb4[idx];
        *reinterpret_cast<float4*>(&ks[idx * 4]) = kk;
        *reinterpret_cast<float4*>(&vs[idx * 4]) = vv;
        kmx = fmaxf(kmx, fmaxf(fmaxf(kk.x, kk.y), fmaxf(kk.z, kk.w)));
        kmn = fminf(kmn, fminf(fminf(kk.x, kk.y), fminf(kk.z, kk.w)));
    }
#pragma unroll
    for (int off = 32; off > 0; off >>= 1) {
        kmx = fmaxf(kmx, __shfl_xor(kmx, off));
        kmn = fminf(kmn, __shfl_xor(kmn, off));
    }
    if (lane == 0) { kred[0][wid] = kmx; kred[1][wid] = kmn; }
    __syncthreads();                              // the ONLY barrier
    kmx = fmaxf(fmaxf(kred[0][0], kred[0][1]), fmaxf(kred[0][2], kred[0][3]));
    kmn = fminf(fminf(kred[1][0], kred[1][1]), fminf(kred[1][2], kred[1][3]));

    // ---- per-wave row constants: lane r (r=lane&7) owns row wid*8+r ----
    const int r8 = lane & 7;
    const int irow0 = rowbase + wid * RPW;
    {
        // nothing
    }
    const float4* xq = reinterpret_cast<const float4*>(xb + (size_t)(irow0 + r8) * CCH);
    float4 a0 = xq[0];
    float4 a1 = xq[1];
    float q = bqv;
    q = fmaf(a0.x, wq[0], q); q = fmaf(a0.y, wq[1], q);
    q = fmaf(a0.z, wq[2], q); q = fmaf(a0.w, wq[3], q);
    q = fmaf(a1.x, wq[4], q); q = fmaf(a1.y, wq[5], q);
    q = fmaf(a1.z, wq[6], q); q = fmaf(a1.w, wq[7], q);
    const float q2v = q * L2E;
    const float m2v = q2v * ((q >= 0.f) ? kmx : kmn);  // exact row max of q2*k

    const float4* ks4 = reinterpret_cast<const float4*>(ks);
    const float4* vs4 = reinterpret_cast<const float4*>(vs);
    float* ap_base = attn + ((size_t)b * NPIX + irow0) * (size_t)NPIX;

    // ---- 8 rows per wave, sequential, no barriers: stores drain under
    //      the next row's stats VALU ----
    for (int rr = 0; rr < RPW; ++rr) {
        const float q2r = __shfl(q2v, rr);
        const float m2r = __shfl(m2v, rr);

        float4 earr[16];
        float s = 0.f, o = 0.f;
#pragma unroll
        for (int g = 0; g < 16; ++g) {
            float4 kk = ks4[lane + g * 64];
            float4 vv = vs4[lane + g * 64];
            float e0 = exp2f(fmaf(q2r, kk.x, -m2r));
            float e1 = exp2f(fmaf(q2r, kk.y, -m2r));
            float e2 = exp2f(fmaf(q2r, kk.z, -m2r));
            float e3 = exp2f(fmaf(q2r, kk.w, -m2r));
            earr[g].x = e0; earr[g].y = e1; earr[g].z = e2; earr[g].w = e3;
            s += (e0 + e1) + (e2 + e3);
            o += fmaf(e0, vv.x, e1 * vv.y) + fmaf(e2, vv.z, e3 * vv.w);
        }
#pragma unroll
        for (int off = 32; off > 0; off >>= 1) {
            s += __shfl_xor(s, off);
            o += __shfl_xor(o, off);
        }
        const float invs = 1.0f / s;

        // y = out*gamma + x for this row (2 lanes)
        const int i = irow0 + rr;
        if (lane < 2) {
            const float og = o * invs * gamma;
            const float4 xv = *reinterpret_cast<const float4*>(xb + (size_t)i * CCH + lane * 4);
            float4 yv = { og + xv.x, og + xv.y, og + xv.z, og + xv.w };
            *reinterpret_cast<float4*>(y + ((size_t)b * NPIX + i) * CCH + lane * 4) = yv;
        }

        // attn row: earr * (1/s), nontemporal coalesced stores
        float* ap = ap_base + (size_t)rr * NPIX;
#pragma unroll
        for (int g = 0; g < 16; ++g) {
            floatx4 e;
            e.x = earr[g].x * invs;
            e.y = earr[g].y * invs;
            e.z = earr[g].z * invs;
            e.w = earr[g].w * invs;
            __builtin_nontemporal_store(e, reinterpret_cast<floatx4*>(ap + lane * 4 + g * 256));
        }
    }
}

// ---------------- fallback: R4 fused single kernel ----------------
#define ROWS 32
#define NP   (BLK/ROWS)
#define SEG  (NPIX/NP)

__global__ __launch_bounds__(BLK) void attn_fused(
    const float* __restrict__ x,
    const float* __restrict__ Wq, const float* __restrict__ bq,
    const float* __restrict__ Wk, const float* __restrict__ bk,
    const float* __restrict__ Wv, const float* __restrict__ bv,
    const float* __restrict__ gamma_p,
    float* __restrict__ y, float* __restrict__ attn)
{
    __shared__ float ks[NPIX];
    __shared__ float vs[NPIX];
    __shared__ float qrow[ROWS];
    __shared__ float crow[ROWS];
    __shared__ float spart[NP][ROWS];
    __shared__ float opart[NP][ROWS];
    __shared__ float kred[2][NW];

    const int b = blockIdx.y;
    const int rowbase = blockIdx.x * ROWS;
    const int tid = threadIdx.x;
    const int wid = tid >> 6;
    const int lane = tid & 63;

    float wq[CCH], wk[CCH], wv[CCH];
#pragma unroll
    for (int c = 0; c < CCH; ++c) { wq[c] = Wq[c]; wk[c] = Wk[c]; wv[c] = Wv[c]; }
    const float bqv = bq[0], bkv = bk[0], bvv = bv[0];
    const float gamma = gamma_p[0];
    const float* xb = x + (size_t)b * NPIX * CCH;

    float kmx = -INFINITY, kmn = INFINITY;
    for (int j = tid; j < NPIX; j += BLK) {
        const float4* xp = reinterpret_cast<const float4*>(xb + (size_t)j * CCH);
        float4 x0 = xp[0];
        float4 x1 = xp[1];
        float kj = bkv;
        kj = fmaf(x0.x, wk[0], kj); kj = fmaf(x0.y, wk[1], kj);
        kj = fmaf(x0.z, wk[2], kj); kj = fmaf(x0.w, wk[3], kj);
        kj = fmaf(x1.x, wk[4], kj); kj = fmaf(x1.y, wk[5], kj);
        kj = fmaf(x1.z, wk[6], kj); kj = fmaf(x1.w, wk[7], kj);
        float vj = bvv;
        vj = fmaf(x0.x, wv[0], vj); vj = fmaf(x0.y, wv[1], vj);
        vj = fmaf(x0.z, wv[2], vj); vj = fmaf(x0.w, wv[3], vj);
        vj = fmaf(x1.x, wv[4], vj); vj = fmaf(x1.y, wv[5], vj);
        vj = fmaf(x1.z, wv[6], vj); vj = fmaf(x1.w, wv[7], vj);
        ks[j] = kj; vs[j] = vj;
        kmx = fmaxf(kmx, kj); kmn = fminf(kmn, kj);
    }
#pragma unroll
    for (int off = 32; off > 0; off >>= 1) {
        kmx = fmaxf(kmx, __shfl_xor(kmx, off));
        kmn = fminf(kmn, __shfl_xor(kmn, off));
    }
    if (lane == 0) { kred[0][wid] = kmx; kred[1][wid] = kmn; }
    __syncthreads();
    kmx = fmaxf(fmaxf(kred[0][0], kred[0][1]), fmaxf(kred[0][2], kred[0][3]));
    kmn = fminf(fminf(kred[1][0], kred[1][1]), fminf(kred[1][2], kred[1][3]));

    const int r = tid & (ROWS - 1);
    const int p = tid >> 5;
    const int i = rowbase + r;
    const float4* xq = reinterpret_cast<const float4*>(xb + (size_t)i * CCH);
    float4 a0 = xq[0];
    float4 a1 = xq[1];
    float q = bqv;
    q = fmaf(a0.x, wq[0], q); q = fmaf(a0.y, wq[1], q);
    q = fmaf(a0.z, wq[2], q); q = fmaf(a0.w, wq[3], q);
    q = fmaf(a1.x, wq[4], q); q = fmaf(a1.y, wq[5], q);
    q = fmaf(a1.z, wq[6], q); q = fmaf(a1.w, wq[7], q);
    const float q2 = q * L2E;
    const float m2 = q2 * ((q >= 0.f) ? kmx : kmn);

    float s0 = 0.f, s1 = 0.f, s2 = 0.f, s3 = 0.f;
    float o0 = 0.f, o1 = 0.f, o2 = 0.f, o3 = 0.f;
    const int j0 = p * SEG;
    for (int j = j0; j < j0 + SEG; j += 4) {
        float4 kk = *reinterpret_cast<const float4*>(&ks[j]);
        float4 vv = *reinterpret_cast<const float4*>(&vs[j]);
        float e0 = exp2f(fmaf(q2, kk.x, -m2));
        float e1 = exp2f(fmaf(q2, kk.y, -m2));
        float e2 = exp2f(fmaf(q2, kk.z, -m2));
        float e3 = exp2f(fmaf(q2, kk.w, -m2));
        s0 += e0; s1 += e1; s2 += e2; s3 += e3;
        o0 = fmaf(e0, vv.x, o0);
        o1 = fmaf(e1, vv.y, o1);
        o2 = fmaf(e2, vv.z, o2);
        o3 = fmaf(e3, vv.w, o3);
    }
    spart[p][r] = (s0 + s1) + (s2 + s3);
    opart[p][r] = (o0 + o1) + (o2 + o3);
    __syncthreads();

    if (tid < ROWS) {
        float s = 0.f, o = 0.f;
#pragma unroll
        for (int pp = 0; pp < NP; ++pp) { s += spart[pp][tid]; o += opart[pp][tid]; }
        const float og = (o / s) * gamma;
        const int i2 = rowbase + tid;
        const float4* xr = reinterpret_cast<const float4*>(xb + (size_t)i2 * CCH);
        float4 b0 = xr[0];
        float4 b1 = xr[1];
        float* yp = y + ((size_t)b * NPIX + i2) * CCH;
        float4 y0 = { og + b0.x, og + b0.y, og + b0.z, og + b0.w };
        float4 y1 = { og + b1.x, og + b1.y, og + b1.z, og + b1.w };
        *reinterpret_cast<float4*>(yp) = y0;
        *reinterpret_cast<float4*>(yp + 4) = y1;
        qrow[tid] = q2;
        crow[tid] = m2 + log2f(s);
    }
    __syncthreads();

    const int j4 = tid * 4;
    float4 kk0 = *reinterpret_cast<const float4*>(&ks[j4]);
    float4 kk1 = *reinterpret_cast<const float4*>(&ks[j4 + 1024]);
    float4 kk2 = *reinterpret_cast<const float4*>(&ks[j4 + 2048]);
    float4 kk3 = *reinterpret_cast<const float4*>(&ks[j4 + 3072]);

    float* ap0 = attn + ((size_t)b * NPIX + rowbase) * (size_t)NPIX;
    for (int rr = 0; rr < ROWS; ++rr) {
        const float qr = qrow[rr];
        const float cr = crow[rr];
        float* ap = ap0 + (size_t)rr * NPIX;
        floatx4 e0, e1, e2, e3;
        e0.x = exp2f(fmaf(qr, kk0.x, -cr)); e0.y = exp2f(fmaf(qr, kk0.y, -cr));
        e0.z = exp2f(fmaf(qr, kk0.z, -cr)); e0.w = exp2f(fmaf(qr, kk0.w, -cr));
        e1.x = exp2f(fmaf(qr, kk1.x, -cr)); e1.y = exp2f(fmaf(qr, kk1.y, -cr));
        e1.z = exp2f(fmaf(qr, kk1.z, -cr)); e1.w = exp2f(fmaf(qr, kk1.w, -cr));
        e2.x = exp2f(fmaf(qr, kk2.x, -cr)); e2.y = exp2f(fmaf(qr, kk2.y, -cr));
        e2.z = exp2f(fmaf(qr, kk2.z, -cr)); e2.w = exp2f(fmaf(qr, kk2.w, -cr));
        e3.x = exp2f(fmaf(qr, kk3.x, -cr)); e3.y = exp2f(fmaf(qr, kk3.y, -cr));
        e3.z = exp2f(fmaf(qr, kk3.z, -cr)); e3.w = exp2f(fmaf(qr, kk3.w, -cr));
        __builtin_nontemporal_store(e0, reinterpret_cast<floatx4*>(&ap[j4]));
        __builtin_nontemporal_store(e1, reinterpret_cast<floatx4*>(&ap[j4 + 1024]));
        __builtin_nontemporal_store(e2, reinterpret_cast<floatx4*>(&ap[j4 + 2048]));
        __builtin_nontemporal_store(e3, reinterpret_cast<floatx4*>(&ap[j4 + 3072]));
    }
}

extern "C" void kernel_launch(void* const* d_in, const int* in_sizes, int n_in,
                              void* d_out, int out_size, void* d_ws, size_t ws_size,
                              hipStream_t stream) {
    const float* x   = (const float*)d_in[0];
    const float* Wq  = (const float*)d_in[1];
    const float* bq  = (const float*)d_in[2];
    const float* Wk  = (const float*)d_in[3];
    const float* bk  = (const float*)d_in[4];
    const float* Wv  = (const float*)d_in[5];
    const float* bv  = (const float*)d_in[6];
    const float* gm  = (const float*)d_in[7];

    const int B = in_sizes[0] / (NPIX * CCH);   // = 8
    float* y    = (float*)d_out;
    float* attn = y + (size_t)B * NPIX * CCH;   // attention follows y, flat

    const size_t kv_bytes = (size_t)B * NPIX * 2 * sizeof(float);  // 256 KB
    if (ws_size >= kv_bytes) {
        float* kbuf = (float*)d_ws;
        float* vbuf = kbuf + (size_t)B * NPIX;
        dim3 gridA(NPIX / 256, B);
        kv_project<<<gridA, 256, 0, stream>>>(x, Wk, bk, Wv, bv, kbuf, vbuf);
        dim3 gridB(NPIX / TILE, B);
        attn_main<<<gridB, BLK, 0, stream>>>(x, Wq, bq, gm, kbuf, vbuf, y, attn);
    } else {
        dim3 grid(NPIX / ROWS, B);
        attn_fused<<<grid, BLK, 0, stream>>>(x, Wq, bq, Wk, bk, Wv, bv, gm, y, attn);
    }
}

// Round 9
// 113.448 us; speedup vs baseline: 1.9069x; 1.9069x over previous
//
#include <hip/hip_runtime.h>
#include <math.h>

#define NPIX 4096        // N = H*W = 64*64
#define CCH 8            // channels
#define BLK 256          // 4 waves per block
#define NW   (BLK/64)
#define RPW  8           // rows per wave
#define TILE (NW*RPW)    // 32 rows per block
#define L2E 1.44269504088896340736f

typedef float floatx4 __attribute__((ext_vector_type(4)));

// ---------------- Kernel A: k/v projection, x read ONCE ----------------
__global__ __launch_bounds__(256) void kv_project(
    const float* __restrict__ x,
    const float* __restrict__ Wk, const float* __restrict__ bk,
    const float* __restrict__ Wv, const float* __restrict__ bv,
    float* __restrict__ kbuf, float* __restrict__ vbuf)
{
    const int b = blockIdx.y;
    const int j = blockIdx.x * 256 + threadIdx.x;

    float wk[CCH], wv[CCH];
#pragma unroll
    for (int c = 0; c < CCH; ++c) { wk[c] = Wk[c]; wv[c] = Wv[c]; }
    const float bkv = bk[0], bvv = bv[0];

    const float4* xp = reinterpret_cast<const float4*>(x + ((size_t)b * NPIX + j) * CCH);
    float4 x0 = xp[0];
    float4 x1 = xp[1];
    float kj = bkv;
    kj = fmaf(x0.x, wk[0], kj); kj = fmaf(x0.y, wk[1], kj);
    kj = fmaf(x0.z, wk[2], kj); kj = fmaf(x0.w, wk[3], kj);
    kj = fmaf(x1.x, wk[4], kj); kj = fmaf(x1.y, wk[5], kj);
    kj = fmaf(x1.z, wk[6], kj); kj = fmaf(x1.w, wk[7], kj);
    float vj = bvv;
    vj = fmaf(x0.x, wv[0], vj); vj = fmaf(x0.y, wv[1], vj);
    vj = fmaf(x0.z, wv[2], vj); vj = fmaf(x0.w, wv[3], vj);
    vj = fmaf(x1.x, wv[4], vj); vj = fmaf(x1.y, wv[5], vj);
    vj = fmaf(x1.z, wv[6], vj); vj = fmaf(x1.w, wv[7], vj);

    kbuf[(size_t)b * NPIX + j] = kj;
    vbuf[(size_t)b * NPIX + j] = vj;
}

// -------- Kernel B: wave-autonomous rows, spill-free, barrier-free --------
__global__ __launch_bounds__(BLK) void attn_main(
    const float* __restrict__ x,
    const float* __restrict__ Wq, const float* __restrict__ bq,
    const float* __restrict__ gamma_p,
    const float* __restrict__ kbuf, const float* __restrict__ vbuf,
    float* __restrict__ y, float* __restrict__ attn)
{
    __shared__ float ks[NPIX];
    __shared__ float vs[NPIX];
    __shared__ float kred[2][NW];

    const int b = blockIdx.y;
    const int rowbase = blockIdx.x * TILE;
    const int tid = threadIdx.x;
    const int wid = tid >> 6;
    const int lane = tid & 63;

    float wq[CCH];
#pragma unroll
    for (int c = 0; c < CCH; ++c) wq[c] = Wq[c];
    const float bqv = bq[0];
    const float gamma = gamma_p[0];

    const float* xb = x + (size_t)b * NPIX * CCH;
    const float4* kb4 = reinterpret_cast<const float4*>(kbuf + (size_t)b * NPIX);
    const float4* vb4 = reinterpret_cast<const float4*>(vbuf + (size_t)b * NPIX);

    // ---- stage k,v into LDS (32 KB from ws); k min/max on the fly ----
    float kmx = -INFINITY, kmn = INFINITY;
#pragma unroll
    for (int i = 0; i < 4; ++i) {
        const int idx = tid + i * 256;           // float4 index
        float4 kk = kb4[idx];
        float4 vv = vb4[idx];
        *reinterpret_cast<float4*>(&ks[idx * 4]) = kk;
        *reinterpret_cast<float4*>(&vs[idx * 4]) = vv;
        kmx = fmaxf(kmx, fmaxf(fmaxf(kk.x, kk.y), fmaxf(kk.z, kk.w)));
        kmn = fminf(kmn, fminf(fminf(kk.x, kk.y), fminf(kk.z, kk.w)));
    }
#pragma unroll
    for (int off = 32; off > 0; off >>= 1) {
        kmx = fmaxf(kmx, __shfl_xor(kmx, off));
        kmn = fminf(kmn, __shfl_xor(kmn, off));
    }
    if (lane == 0) { kred[0][wid] = kmx; kred[1][wid] = kmn; }
    __syncthreads();                              // the ONLY barrier
    kmx = fmaxf(fmaxf(kred[0][0], kred[0][1]), fmaxf(kred[0][2], kred[0][3]));
    kmn = fminf(fminf(kred[1][0], kred[1][1]), fminf(kred[1][2], kred[1][3]));

    // ---- per-wave row constants: lane's (lane&7) row of this wave's 8 ----
    const int r8 = lane & 7;
    const int irow0 = rowbase + wid * RPW;
    const float4* xq = reinterpret_cast<const float4*>(xb + (size_t)(irow0 + r8) * CCH);
    float4 a0 = xq[0];
    float4 a1 = xq[1];
    float q = bqv;
    q = fmaf(a0.x, wq[0], q); q = fmaf(a0.y, wq[1], q);
    q = fmaf(a0.z, wq[2], q); q = fmaf(a0.w, wq[3], q);
    q = fmaf(a1.x, wq[4], q); q = fmaf(a1.y, wq[5], q);
    q = fmaf(a1.z, wq[6], q); q = fmaf(a1.w, wq[7], q);
    const float q2v = q * L2E;
    const float m2v = q2v * ((q >= 0.f) ? kmx : kmn);  // exact row max of q2*k

    const float4* ks4 = reinterpret_cast<const float4*>(ks);
    const float4* vs4 = reinterpret_cast<const float4*>(vs);
    float* ap_base = attn + ((size_t)b * NPIX + irow0) * (size_t)NPIX;

    // ---- 8 rows per wave, sequential, barrier-free; stores fire-and-forget
    //      and drain while the next row's stats run on the VALU ----
    for (int rr = 0; rr < RPW; ++rr) {
        const float q2r = __shfl(q2v, rr);
        const float m2r = __shfl(m2v, rr);

        // stats sweep: 64 cols per lane, NO exponential caching (no spills)
        float s = 0.f, o = 0.f;
#pragma unroll
        for (int g = 0; g < 16; ++g) {
            float4 kk = ks4[lane + g * 64];
            float4 vv = vs4[lane + g * 64];
            float e0 = exp2f(fmaf(q2r, kk.x, -m2r));
            float e1 = exp2f(fmaf(q2r, kk.y, -m2r));
            float e2 = exp2f(fmaf(q2r, kk.z, -m2r));
            float e3 = exp2f(fmaf(q2r, kk.w, -m2r));
            s += (e0 + e1) + (e2 + e3);
            o += fmaf(e0, vv.x, e1 * vv.y) + fmaf(e2, vv.z, e3 * vv.w);
        }
#pragma unroll
        for (int off = 32; off > 0; off >>= 1) {
            s += __shfl_xor(s, off);
            o += __shfl_xor(o, off);
        }
        const float invs = 1.0f / s;

        // y = out*gamma + x for this row (2 lanes)
        const int i = irow0 + rr;
        if (lane < 2) {
            const float og = o * invs * gamma;
            const float4 xv = *reinterpret_cast<const float4*>(xb + (size_t)i * CCH + lane * 4);
            float4 yv = { og + xv.x, og + xv.y, og + xv.z, og + xv.w };
            *reinterpret_cast<float4*>(y + ((size_t)b * NPIX + i) * CCH + lane * 4) = yv;
        }

        // store pass: recompute exp2, scale by 1/s, nontemporal coalesced
        float* ap = ap_base + (size_t)rr * NPIX;
#pragma unroll
        for (int g = 0; g < 16; ++g) {
            float4 kk = ks4[lane + g * 64];
            floatx4 e;
            e.x = exp2f(fmaf(q2r, kk.x, -m2r)) * invs;
            e.y = exp2f(fmaf(q2r, kk.y, -m2r)) * invs;
            e.z = exp2f(fmaf(q2r, kk.z, -m2r)) * invs;
            e.w = exp2f(fmaf(q2r, kk.w, -m2r)) * invs;
            __builtin_nontemporal_store(e, reinterpret_cast<floatx4*>(ap + (lane + g * 64) * 4));
        }
    }
}

// ---------------- fallback: R4 fused single kernel ----------------
#define ROWS 32
#define NP   (BLK/ROWS)
#define SEG  (NPIX/NP)

__global__ __launch_bounds__(BLK) void attn_fused(
    const float* __restrict__ x,
    const float* __restrict__ Wq, const float* __restrict__ bq,
    const float* __restrict__ Wk, const float* __restrict__ bk,
    const float* __restrict__ Wv, const float* __restrict__ bv,
    const float* __restrict__ gamma_p,
    float* __restrict__ y, float* __restrict__ attn)
{
    __shared__ float ks[NPIX];
    __shared__ float vs[NPIX];
    __shared__ float qrow[ROWS];
    __shared__ float crow[ROWS];
    __shared__ float spart[NP][ROWS];
    __shared__ float opart[NP][ROWS];
    __shared__ float kred[2][NW];

    const int b = blockIdx.y;
    const int rowbase = blockIdx.x * ROWS;
    const int tid = threadIdx.x;
    const int wid = tid >> 6;
    const int lane = tid & 63;

    float wq[CCH], wk[CCH], wv[CCH];
#pragma unroll
    for (int c = 0; c < CCH; ++c) { wq[c] = Wq[c]; wk[c] = Wk[c]; wv[c] = Wv[c]; }
    const float bqv = bq[0], bkv = bk[0], bvv = bv[0];
    const float gamma = gamma_p[0];
    const float* xb = x + (size_t)b * NPIX * CCH;

    float kmx = -INFINITY, kmn = INFINITY;
    for (int j = tid; j < NPIX; j += BLK) {
        const float4* xp = reinterpret_cast<const float4*>(xb + (size_t)j * CCH);
        float4 x0 = xp[0];
        float4 x1 = xp[1];
        float kj = bkv;
        kj = fmaf(x0.x, wk[0], kj); kj = fmaf(x0.y, wk[1], kj);
        kj = fmaf(x0.z, wk[2], kj); kj = fmaf(x0.w, wk[3], kj);
        kj = fmaf(x1.x, wk[4], kj); kj = fmaf(x1.y, wk[5], kj);
        kj = fmaf(x1.z, wk[6], kj); kj = fmaf(x1.w, wk[7], kj);
        float vj = bvv;
        vj = fmaf(x0.x, wv[0], vj); vj = fmaf(x0.y, wv[1], vj);
        vj = fmaf(x0.z, wv[2], vj); vj = fmaf(x0.w, wv[3], vj);
        vj = fmaf(x1.x, wv[4], vj); vj = fmaf(x1.y, wv[5], vj);
        vj = fmaf(x1.z, wv[6], vj); vj = fmaf(x1.w, wv[7], vj);
        ks[j] = kj; vs[j] = vj;
        kmx = fmaxf(kmx, kj); kmn = fminf(kmn, kj);
    }
#pragma unroll
    for (int off = 32; off > 0; off >>= 1) {
        kmx = fmaxf(kmx, __shfl_xor(kmx, off));
        kmn = fminf(kmn, __shfl_xor(kmn, off));
    }
    if (lane == 0) { kred[0][wid] = kmx; kred[1][wid] = kmn; }
    __syncthreads();
    kmx = fmaxf(fmaxf(kred[0][0], kred[0][1]), fmaxf(kred[0][2], kred[0][3]));
    kmn = fminf(fminf(kred[1][0], kred[1][1]), fminf(kred[1][2], kred[1][3]));

    const int r = tid & (ROWS - 1);
    const int p = tid >> 5;
    const int i = rowbase + r;
    const float4* xq = reinterpret_cast<const float4*>(xb + (size_t)i * CCH);
    float4 a0 = xq[0];
    float4 a1 = xq[1];
    float q = bqv;
    q = fmaf(a0.x, wq[0], q); q = fmaf(a0.y, wq[1], q);
    q = fmaf(a0.z, wq[2], q); q = fmaf(a0.w, wq[3], q);
    q = fmaf(a1.x, wq[4], q); q = fmaf(a1.y, wq[5], q);
    q = fmaf(a1.z, wq[6], q); q = fmaf(a1.w, wq[7], q);
    const float q2 = q * L2E;
    const float m2 = q2 * ((q >= 0.f) ? kmx : kmn);

    float s0 = 0.f, s1 = 0.f, s2 = 0.f, s3 = 0.f;
    float o0 = 0.f, o1 = 0.f, o2 = 0.f, o3 = 0.f;
    const int j0 = p * SEG;
    for (int j = j0; j < j0 + SEG; j += 4) {
        float4 kk = *reinterpret_cast<const float4*>(&ks[j]);
        float4 vv = *reinterpret_cast<const float4*>(&vs[j]);
        float e0 = exp2f(fmaf(q2, kk.x, -m2));
        float e1 = exp2f(fmaf(q2, kk.y, -m2));
        float e2 = exp2f(fmaf(q2, kk.z, -m2));
        float e3 = exp2f(fmaf(q2, kk.w, -m2));
        s0 += e0; s1 += e1; s2 += e2; s3 += e3;
        o0 = fmaf(e0, vv.x, o0);
        o1 = fmaf(e1, vv.y, o1);
        o2 = fmaf(e2, vv.z, o2);
        o3 = fmaf(e3, vv.w, o3);
    }
    spart[p][r] = (s0 + s1) + (s2 + s3);
    opart[p][r] = (o0 + o1) + (o2 + o3);
    __syncthreads();

    if (tid < ROWS) {
        float s = 0.f, o = 0.f;
#pragma unroll
        for (int pp = 0; pp < NP; ++pp) { s += spart[pp][tid]; o += opart[pp][tid]; }
        const float og = (o / s) * gamma;
        const int i2 = rowbase + tid;
        const float4* xr = reinterpret_cast<const float4*>(xb + (size_t)i2 * CCH);
        float4 b0 = xr[0];
        float4 b1 = xr[1];
        float* yp = y + ((size_t)b * NPIX + i2) * CCH;
        float4 y0 = { og + b0.x, og + b0.y, og + b0.z, og + b0.w };
        float4 y1 = { og + b1.x, og + b1.y, og + b1.z, og + b1.w };
        *reinterpret_cast<float4*>(yp) = y0;
        *reinterpret_cast<float4*>(yp + 4) = y1;
        qrow[tid] = q2;
        crow[tid] = m2 + log2f(s);
    }
    __syncthreads();

    const int j4 = tid * 4;
    float4 kk0 = *reinterpret_cast<const float4*>(&ks[j4]);
    float4 kk1 = *reinterpret_cast<const float4*>(&ks[j4 + 1024]);
    float4 kk2 = *reinterpret_cast<const float4*>(&ks[j4 + 2048]);
    float4 kk3 = *reinterpret_cast<const float4*>(&ks[j4 + 3072]);

    float* ap0 = attn + ((size_t)b * NPIX + rowbase) * (size_t)NPIX;
    for (int rr = 0; rr < ROWS; ++rr) {
        const float qr = qrow[rr];
        const float cr = crow[rr];
        float* ap = ap0 + (size_t)rr * NPIX;
        floatx4 e0, e1, e2, e3;
        e0.x = exp2f(fmaf(qr, kk0.x, -cr)); e0.y = exp2f(fmaf(qr, kk0.y, -cr));
        e0.z = exp2f(fmaf(qr, kk0.z, -cr)); e0.w = exp2f(fmaf(qr, kk0.w, -cr));
        e1.x = exp2f(fmaf(qr, kk1.x, -cr)); e1.y = exp2f(fmaf(qr, kk1.y, -cr));
        e1.z = exp2f(fmaf(qr, kk1.z, -cr)); e1.w = exp2f(fmaf(qr, kk1.w, -cr));
        e2.x = exp2f(fmaf(qr, kk2.x, -cr)); e2.y = exp2f(fmaf(qr, kk2.y, -cr));
        e2.z = exp2f(fmaf(qr, kk2.z, -cr)); e2.w = exp2f(fmaf(qr, kk2.w, -cr));
        e3.x = exp2f(fmaf(qr, kk3.x, -cr)); e3.y = exp2f(fmaf(qr, kk3.y, -cr));
        e3.z = exp2f(fmaf(qr, kk3.z, -cr)); e3.w = exp2f(fmaf(qr, kk3.w, -cr));
        __builtin_nontemporal_store(e0, reinterpret_cast<floatx4*>(&ap[j4]));
        __builtin_nontemporal_store(e1, reinterpret_cast<floatx4*>(&ap[j4 + 1024]));
        __builtin_nontemporal_store(e2, reinterpret_cast<floatx4*>(&ap[j4 + 2048]));
        __builtin_nontemporal_store(e3, reinterpret_cast<floatx4*>(&ap[j4 + 3072]));
    }
}

extern "C" void kernel_launch(void* const* d_in, const int* in_sizes, int n_in,
                              void* d_out, int out_size, void* d_ws, size_t ws_size,
                              hipStream_t stream) {
    const float* x   = (const float*)d_in[0];
    const float* Wq  = (const float*)d_in[1];
    const float* bq  = (const float*)d_in[2];
    const float* Wk  = (const float*)d_in[3];
    const float* bk  = (const float*)d_in[4];
    const float* Wv  = (const float*)d_in[5];
    const float* bv  = (const float*)d_in[6];
    const float* gm  = (const float*)d_in[7];

    const int B = in_sizes[0] / (NPIX * CCH);   // = 8
    float* y    = (float*)d_out;
    float* attn = y + (size_t)B * NPIX * CCH;   // attention follows y, flat

    const size_t kv_bytes = (size_t)B * NPIX * 2 * sizeof(float);  // 256 KB
    if (ws_size >= kv_bytes) {
        float* kbuf = (float*)d_ws;
        float* vbuf = kbuf + (size_t)B * NPIX;
        dim3 gridA(NPIX / 256, B);
        kv_project<<<gridA, 256, 0, stream>>>(x, Wk, bk, Wv, bv, kbuf, vbuf);
        dim3 gridB(NPIX / TILE, B);
        attn_main<<<gridB, BLK, 0, stream>>>(x, Wq, bq, gm, kbuf, vbuf, y, attn);
    } else {
        dim3 grid(NPIX / ROWS, B);
        attn_fused<<<grid, BLK, 0, stream>>>(x, Wq, bq, Wk, bk, Wv, bv, gm, y, attn);
    }
}